// Round 13
// baseline (74.104 us; speedup 1.0000x reference)
//
#include <hip/hip_runtime.h>

// DGCLoss: 1 - mean NDCG. N=384 rows, D=256 feats, M=383 off-diag cols.
//
// Round 13: (a) 3->2 launches: dgc_final removed, per-row relaxed
// atomicAdd(out, -ndcg/N) (R11 measured the atomic tail ~0.2us vs ~1.5-2us
// for the extra kernel+gap); out=1.0 init in normT's table block.
// (b) pair-rcp soft loop: 1/(1+a)+1/(1+b) = (2+a+b)*rcp(1+(a+b)+ab) -- 3
// trans per 2 terms instead of 4 (trans issue = 16cyc/wave64 dominates).
// Window bounds |ri-v|<=~18 => ab <= 7e10, fp32-safe. WWIN stays 6
// (absmax 9.8e-4 vs 3.6e-3 threshold -- accuracy floor reached).
//   dgc_normT : 25 blocks: 0-23 transpose+normalize -> XT/XN; 24 idcg_tab + out=1.
//   dgc_fused : block = rows (2b,2b+1): shared XT gram -> 2 srows, counting
//               sorts, pair-rcp soft window, atomicAdd(out, -ndcg/N).

#define NN 384
#define DD 256
#define MM 383
// exp(-d*1000) == exp2(s_i - s_j) with s = ((cos+1)*0.5) * 1000*log2(e)
#define HSCALE 721.3475204444817f   // 0.5 * 1000 * log2(e)
#define NBUCK  256
#define BSCALE 0.1767955801104972f  // 256 / 1448  (values in [0, 1442.7])
#define WWIN   6.0f                 // soft-window half-width in s-units

__global__ __launch_bounds__(256) void dgc_normT(const float* __restrict__ x,
                                                 const int* __restrict__ gt,
                                                 float* __restrict__ XT,
                                                 float* __restrict__ XN,
                                                 float* __restrict__ idcg_tab,
                                                 float* __restrict__ out) {
    const int t = threadIdx.x;

    if (blockIdx.x == 24) {
        // ---- idcg table (idcg depends only on gt[n]); also out = 1.0 ----
        __shared__ int   cnt[6];
        __shared__ int   cum[6][6];
        __shared__ float wred[4][6];
        const int lane = t & 63;
        const int wave = t >> 6;

        if (t == 0) out[0] = 1.0f;
        if (t < 6) cnt[t] = 0;
        __syncthreads();
        atomicAdd(&cnt[gt[t]], 1);                    // t: 0..255
        if (t + 256 < NN) atomicAdd(&cnt[gt[t + 256]], 1);
        __syncthreads();
        if (t < 6) {                                  // t = gv
            int h[6];
            #pragma unroll
            for (int g = 0; g < 6; ++g) h[g] = 0;
            #pragma unroll
            for (int v = 0; v < 6; ++v) {
                int d = v - t; d = d < 0 ? -d : d;
                h[d] += cnt[v];
            }
            h[0] -= 1;                                // remove self term
            int s = 0;
            #pragma unroll
            for (int g = 0; g < 6; ++g) { s += h[g]; cum[t][g] = s; }
        }
        __syncthreads();

        float acc[6] = {0.f, 0.f, 0.f, 0.f, 0.f, 0.f};
        for (int p = t; p < MM; p += 256) {
            const float invl = 1.0f / __builtin_amdgcn_logf((float)(p + 2));
            #pragma unroll
            for (int gv = 0; gv < 6; ++gv) {
                const int g = (p >= cum[gv][0]) + (p >= cum[gv][1])
                            + (p >= cum[gv][2]) + (p >= cum[gv][3])
                            + (p >= cum[gv][4]);
                acc[gv] += (float)((1 << (10 - g)) - 1) * invl;
            }
        }
        for (int off = 32; off > 0; off >>= 1) {
            #pragma unroll
            for (int gv = 0; gv < 6; ++gv) acc[gv] += __shfl_down(acc[gv], off, 64);
        }
        if (lane == 0) {
            #pragma unroll
            for (int gv = 0; gv < 6; ++gv) wred[wave][gv] = acc[gv];
        }
        __syncthreads();
        if (t < 6) idcg_tab[t] = wred[0][t] + wred[1][t] + wred[2][t] + wred[3][t];
        return;
    }

    // ---- transpose + normalize (blocks 0..23) ----
    __shared__ float xs[16][260];   // +4 pad: conflict-free
    __shared__ float invn[16];
    const int r0 = blockIdx.x * 16;

    #pragma unroll
    for (int i = 0; i < 4; ++i) {
        int f = t + i * 256;            // float4 unit 0..1023
        int r = f >> 6, c4 = f & 63;
        float4 v = ((const float4*)(x + (size_t)(r0 + r) * DD))[c4];
        xs[r][c4 * 4 + 0] = v.x; xs[r][c4 * 4 + 1] = v.y;
        xs[r][c4 * 4 + 2] = v.z; xs[r][c4 * 4 + 3] = v.w;
    }
    __syncthreads();

    {   // row norms: 16 threads per row
        const int r = t >> 4, sub = t & 15;
        float s = 0.0f;
        #pragma unroll
        for (int m = 0; m < 16; ++m) {
            float v = xs[r][sub * 16 + m];
            s = fmaf(v, v, s);
        }
        #pragma unroll
        for (int off = 8; off > 0; off >>= 1) s += __shfl_xor(s, off, 64);
        if (sub == 0) invn[r] = __builtin_amdgcn_rsqf(fmaxf(s, 1e-16f));
    }
    __syncthreads();

    {   // normalized transpose XT[k][r0+r]
        const int r  = t & 15;
        const int kk = t >> 4;
        const float inv = invn[r];
        #pragma unroll
        for (int i = 0; i < 16; ++i) {
            int k = i * 16 + kk;
            XT[(size_t)k * NN + r0 + r] = xs[r][k] * inv;
        }
    }
    {   // normalized row-major XN (coalesced)
        #pragma unroll
        for (int i = 0; i < 4; ++i) {
            int f = t + i * 256;
            int r = f >> 6, c4 = f & 63;
            const float inv = invn[r];
            float4 v;
            v.x = xs[r][c4 * 4 + 0] * inv; v.y = xs[r][c4 * 4 + 1] * inv;
            v.z = xs[r][c4 * 4 + 2] * inv; v.w = xs[r][c4 * 4 + 3] * inv;
            ((float4*)(XN + (size_t)(r0 + r) * DD))[c4] = v;
        }
    }
}

__global__ __launch_bounds__(768) void dgc_fused(const float* __restrict__ XT,
                                                 const float* __restrict__ XN,
                                                 const int* __restrict__ gt,
                                                 const float* __restrict__ idcg_tab,
                                                 float* __restrict__ out) {
    __shared__ float  xs[2][DD];        // normalized rows n0, n0+1
    __shared__ float4 pacc[2][8][96];   // [row][k-chunk][j4] partial dots
    __shared__ float  srow[2][NN];
    __shared__ float  vsort[2][NN];
    __shared__ int    sidx[2][NN];
    __shared__ int    hist[2][NBUCK];
    __shared__ int    pre[2][NBUCK + 1];
    __shared__ float  redd[12];

    const int n0   = blockIdx.x * 2;
    const int t    = threadIdx.x;
    const int lane = t & 63;
    const int wave = t >> 6;

    if (t < 128)
        ((float4*)xs[t >> 6])[t & 63] =
            ((const float4*)(XN + (size_t)(n0 + (t >> 6)) * DD))[t & 63];
    if (t < 512) ((int*)hist)[t] = 0;
    __syncthreads();

    // ---- gram: j4 = t%96 (4 cols), kc = t/96 (8 chunks of 32 k's).
    //      Each XT float4 loaded ONCE, fma'd into both rows. ----
    {
        const int j4 = t % 96;
        const int kc = t / 96;                 // 0..7
        const float4* XT4 = (const float4*)XT;
        float4 a0 = {0.f, 0.f, 0.f, 0.f};
        float4 a1 = {0.f, 0.f, 0.f, 0.f};
        const int k0 = kc * 32;
        #pragma unroll 8
        for (int m = 0; m < 32; ++m) {
            const int k = k0 + m;
            float4 b = XT4[(size_t)k * 96 + j4];   // coalesced, loaded once
            float s0 = xs[0][k];
            float s1 = xs[1][k];
            a0.x = fmaf(s0, b.x, a0.x); a0.y = fmaf(s0, b.y, a0.y);
            a0.z = fmaf(s0, b.z, a0.z); a0.w = fmaf(s0, b.w, a0.w);
            a1.x = fmaf(s1, b.x, a1.x); a1.y = fmaf(s1, b.y, a1.y);
            a1.z = fmaf(s1, b.z, a1.z); a1.w = fmaf(s1, b.w, a1.w);
        }
        pacc[0][kc][j4] = a0;
        pacc[1][kc][j4] = a1;
    }
    __syncthreads();

    const int r = t / 384;                 // row-half: waves 0-5 -> 0, 6-11 -> 1
    const int u = t - r * 384;             // 0..383

    {   // reduce 8 k-chunks; flat float view per row: [kc*384 + u]
        const float* pf = (const float*)pacc[r];
        float dot = 0.0f;
        #pragma unroll
        for (int c = 0; c < 8; ++c) dot += pf[c * 384 + u];
        srow[r][u] = fmaf(dot, HSCALE, HSCALE);
    }
    __syncthreads();

    // ---- counting sort per row ----
    const float vraw = srow[r][u];
    int b = (int)(vraw * BSCALE);
    b = b < 0 ? 0 : (b > NBUCK - 1 ? NBUCK - 1 : b);
    const int slot = atomicAdd(&hist[r][b], 1);
    __syncthreads();

    if (wave == 0 || wave == 6) {          // one scan wave per row
        const int rr = wave / 6;
        const int s0 = hist[rr][lane * 4 + 0], s1 = hist[rr][lane * 4 + 1];
        const int s2 = hist[rr][lane * 4 + 2], s3 = hist[rr][lane * 4 + 3];
        const int sum = s0 + s1 + s2 + s3;
        int inc = sum;
        #pragma unroll
        for (int off = 1; off < 64; off <<= 1) {
            int uu = __shfl_up(inc, off, 64);
            if (lane >= off) inc += uu;
        }
        const int base = inc - sum;
        pre[rr][lane * 4 + 0] = base;
        pre[rr][lane * 4 + 1] = base + s0;
        pre[rr][lane * 4 + 2] = base + s0 + s1;
        pre[rr][lane * 4 + 3] = base + s0 + s1 + s2;
        if (lane == 63) pre[rr][NBUCK] = inc;    // = 384
    }
    __syncthreads();

    {
        const int pos = pre[r][b] + slot;
        vsort[r][pos] = vraw;
        sidx[r][pos]  = u;
    }
    __syncthreads();

    // ---- soft window at sorted position u of row r ----
    const int   nrow  = n0 + r;
    const float ri    = vsort[r][u];
    const int   iorig = sidx[r][u];
    const float sn    = srow[r][nrow];

    int Blo = (int)((ri - WWIN) * BSCALE);
    int Bhi = (int)((ri + WWIN) * BSCALE);
    Blo = Blo < 0 ? 0 : (Blo > NBUCK - 1 ? NBUCK - 1 : Blo);
    Bhi = Bhi < 0 ? 0 : (Bhi > NBUCK - 1 ? NBUCK - 1 : Bhi);
    const int lo = pre[r][Blo];        // below: term ~ 0
    const int hi = pre[r][Bhi + 1];    // at/above: term ~ 1

    // pair-rcp: 1/(1+a) + 1/(1+b) = (2+(a+b)) * rcp(1+(a+b)+a*b)
    float acc = 0.0f;
    int q = lo;
    for (; q + 2 <= hi; q += 2) {
        float a = __builtin_amdgcn_exp2f(ri - vsort[r][q]);
        float bb = __builtin_amdgcn_exp2f(ri - vsort[r][q + 1]);
        float e = a + bb;
        float f = a * bb;
        acc = fmaf(2.0f + e, __builtin_amdgcn_rcpf(1.0f + e + f), acc);
    }
    if (q < hi)
        acc += __builtin_amdgcn_rcpf(1.0f + __builtin_amdgcn_exp2f(ri - vsort[r][q]));
    float sum_all = (float)(NN - hi) + acc;

    // diagonal (c == nrow) correction, bucket-consistent with the window
    int bn = (int)(sn * BSCALE);
    bn = bn < 0 ? 0 : (bn > NBUCK - 1 ? NBUCK - 1 : bn);
    float cd = 0.0f;
    if (bn > Bhi)       cd = 1.0f;
    else if (bn >= Blo) cd = __builtin_amdgcn_rcpf(1.0f + __builtin_amdgcn_exp2f(ri - sn));
    // self term (sigma(0)=0.5) always in-window: ind = 1 + sum - 0.5 - cd
    const float ind = 0.5f + sum_all - cd;

    // ---- dcg term ----
    float dcg_i = 0.0f;
    if (iorig != nrow) {               // permutation covers all 383 real cols
        const int gd = gt[iorig] - gt[nrow];
        const int gg = gd < 0 ? -gd : gd;
        dcg_i = (float)((1 << (10 - gg)) - 1) / __builtin_amdgcn_logf(ind + 1.0f);
    }

    #pragma unroll
    for (int off = 32; off > 0; off >>= 1) dcg_i += __shfl_down(dcg_i, off, 64);
    if (lane == 0) redd[wave] = dcg_i;
    __syncthreads();
    if (t == 0) {
        float d = redd[0] + redd[1] + redd[2] + redd[3] + redd[4] + redd[5];
        atomicAdd(out, -d / (idcg_tab[gt[n0]] * (float)NN));
    }
    if (t == 384) {
        float d = redd[6] + redd[7] + redd[8] + redd[9] + redd[10] + redd[11];
        atomicAdd(out, -d / (idcg_tab[gt[n0 + 1]] * (float)NN));
    }
}

extern "C" void kernel_launch(void* const* d_in, const int* in_sizes, int n_in,
                              void* d_out, int out_size, void* d_ws, size_t ws_size,
                              hipStream_t stream) {
    const float* ranking = (const float*)d_in[0];
    const int*   gt      = (const int*)d_in[1];
    float*       out     = (float*)d_out;

    float* XT  = (float*)d_ws;                  // 256*384
    float* XN  = XT + (size_t)DD * NN;          // 384*256
    float* tab = XN + (size_t)NN * DD;          // 6 (+pad)

    dgc_normT<<<25, 256, 0, stream>>>(ranking, gt, XT, XN, tab, out);
    dgc_fused<<<NN / 2, 768, 0, stream>>>(XT, XN, gt, tab, out);
}

// Round 14
// 69.412 us; speedup vs baseline: 1.0676x; 1.0676x over previous
//
#include <hip/hip_runtime.h>

// DGCLoss: 1 - mean NDCG. N=384 rows, D=256 feats, M=383 off-diag cols.
//
// Round 14: R12 structure EXACTLY (3 kernels, plain ndcg stores, final
// reduce -- R13's bundled revert to 384 same-line atomicAdds regressed +4us:
// single-round grids expose the serialized cross-XCD atomic tail) + the ONE
// new lever: pair-rcp soft loop (3 trans per 2 terms instead of 4).
//   dgc_normT : 25 blocks: 0-23 transpose+normalize -> XT/XN; 24 idcg_tab.
//   dgc_fused : block = rows (2b,2b+1): shared XT gram -> 2 srows, counting
//               sorts, pair-rcp soft window, ndcg[n] stores.
//   dgc_final : 1 block: out = 1 - mean(ndcg).

#define NN 384
#define DD 256
#define MM 383
// exp(-d*1000) == exp2(s_i - s_j) with s = ((cos+1)*0.5) * 1000*log2(e)
#define HSCALE 721.3475204444817f   // 0.5 * 1000 * log2(e)
#define NBUCK  256
#define BSCALE 0.1767955801104972f  // 256 / 1448  (values in [0, 1442.7])
#define WWIN   6.0f                 // soft-window half-width in s-units

__global__ __launch_bounds__(256) void dgc_normT(const float* __restrict__ x,
                                                 const int* __restrict__ gt,
                                                 float* __restrict__ XT,
                                                 float* __restrict__ XN,
                                                 float* __restrict__ idcg_tab) {
    const int t = threadIdx.x;

    if (blockIdx.x == 24) {
        // ---- idcg table: idcg depends only on gt[n] ----
        __shared__ int   cnt[6];
        __shared__ int   cum[6][6];
        __shared__ float wred[4][6];
        const int lane = t & 63;
        const int wave = t >> 6;

        if (t < 6) cnt[t] = 0;
        __syncthreads();
        atomicAdd(&cnt[gt[t]], 1);                    // t: 0..255
        if (t + 256 < NN) atomicAdd(&cnt[gt[t + 256]], 1);
        __syncthreads();
        if (t < 6) {                                  // t = gv
            int h[6];
            #pragma unroll
            for (int g = 0; g < 6; ++g) h[g] = 0;
            #pragma unroll
            for (int v = 0; v < 6; ++v) {
                int d = v - t; d = d < 0 ? -d : d;
                h[d] += cnt[v];
            }
            h[0] -= 1;                                // remove self term
            int s = 0;
            #pragma unroll
            for (int g = 0; g < 6; ++g) { s += h[g]; cum[t][g] = s; }
        }
        __syncthreads();

        float acc[6] = {0.f, 0.f, 0.f, 0.f, 0.f, 0.f};
        for (int p = t; p < MM; p += 256) {
            const float invl = 1.0f / __builtin_amdgcn_logf((float)(p + 2));
            #pragma unroll
            for (int gv = 0; gv < 6; ++gv) {
                const int g = (p >= cum[gv][0]) + (p >= cum[gv][1])
                            + (p >= cum[gv][2]) + (p >= cum[gv][3])
                            + (p >= cum[gv][4]);
                acc[gv] += (float)((1 << (10 - g)) - 1) * invl;
            }
        }
        for (int off = 32; off > 0; off >>= 1) {
            #pragma unroll
            for (int gv = 0; gv < 6; ++gv) acc[gv] += __shfl_down(acc[gv], off, 64);
        }
        if (lane == 0) {
            #pragma unroll
            for (int gv = 0; gv < 6; ++gv) wred[wave][gv] = acc[gv];
        }
        __syncthreads();
        if (t < 6) idcg_tab[t] = wred[0][t] + wred[1][t] + wred[2][t] + wred[3][t];
        return;
    }

    // ---- transpose + normalize (blocks 0..23) ----
    __shared__ float xs[16][260];   // +4 pad: conflict-free
    __shared__ float invn[16];
    const int r0 = blockIdx.x * 16;

    #pragma unroll
    for (int i = 0; i < 4; ++i) {
        int f = t + i * 256;            // float4 unit 0..1023
        int r = f >> 6, c4 = f & 63;
        float4 v = ((const float4*)(x + (size_t)(r0 + r) * DD))[c4];
        xs[r][c4 * 4 + 0] = v.x; xs[r][c4 * 4 + 1] = v.y;
        xs[r][c4 * 4 + 2] = v.z; xs[r][c4 * 4 + 3] = v.w;
    }
    __syncthreads();

    {   // row norms: 16 threads per row
        const int r = t >> 4, sub = t & 15;
        float s = 0.0f;
        #pragma unroll
        for (int m = 0; m < 16; ++m) {
            float v = xs[r][sub * 16 + m];
            s = fmaf(v, v, s);
        }
        #pragma unroll
        for (int off = 8; off > 0; off >>= 1) s += __shfl_xor(s, off, 64);
        if (sub == 0) invn[r] = __builtin_amdgcn_rsqf(fmaxf(s, 1e-16f));
    }
    __syncthreads();

    {   // normalized transpose XT[k][r0+r]
        const int r  = t & 15;
        const int kk = t >> 4;
        const float inv = invn[r];
        #pragma unroll
        for (int i = 0; i < 16; ++i) {
            int k = i * 16 + kk;
            XT[(size_t)k * NN + r0 + r] = xs[r][k] * inv;
        }
    }
    {   // normalized row-major XN (coalesced)
        #pragma unroll
        for (int i = 0; i < 4; ++i) {
            int f = t + i * 256;
            int r = f >> 6, c4 = f & 63;
            const float inv = invn[r];
            float4 v;
            v.x = xs[r][c4 * 4 + 0] * inv; v.y = xs[r][c4 * 4 + 1] * inv;
            v.z = xs[r][c4 * 4 + 2] * inv; v.w = xs[r][c4 * 4 + 3] * inv;
            ((float4*)(XN + (size_t)(r0 + r) * DD))[c4] = v;
        }
    }
}

__global__ __launch_bounds__(768) void dgc_fused(const float* __restrict__ XT,
                                                 const float* __restrict__ XN,
                                                 const int* __restrict__ gt,
                                                 const float* __restrict__ idcg_tab,
                                                 float* __restrict__ ndcg) {
    __shared__ float  xs[2][DD];        // normalized rows n0, n0+1
    __shared__ float4 pacc[2][8][96];   // [row][k-chunk][j4] partial dots
    __shared__ float  srow[2][NN];
    __shared__ float  vsort[2][NN];
    __shared__ int    sidx[2][NN];
    __shared__ int    hist[2][NBUCK];
    __shared__ int    pre[2][NBUCK + 1];
    __shared__ float  redd[12];

    const int n0   = blockIdx.x * 2;
    const int t    = threadIdx.x;
    const int lane = t & 63;
    const int wave = t >> 6;

    if (t < 128)
        ((float4*)xs[t >> 6])[t & 63] =
            ((const float4*)(XN + (size_t)(n0 + (t >> 6)) * DD))[t & 63];
    if (t < 512) ((int*)hist)[t] = 0;
    __syncthreads();

    // ---- gram: j4 = t%96 (4 cols), kc = t/96 (8 chunks of 32 k's).
    //      Each XT float4 loaded ONCE, fma'd into both rows. ----
    {
        const int j4 = t % 96;
        const int kc = t / 96;                 // 0..7
        const float4* XT4 = (const float4*)XT;
        float4 a0 = {0.f, 0.f, 0.f, 0.f};
        float4 a1 = {0.f, 0.f, 0.f, 0.f};
        const int k0 = kc * 32;
        #pragma unroll 8
        for (int m = 0; m < 32; ++m) {
            const int k = k0 + m;
            float4 b = XT4[(size_t)k * 96 + j4];   // coalesced, loaded once
            float s0 = xs[0][k];
            float s1 = xs[1][k];
            a0.x = fmaf(s0, b.x, a0.x); a0.y = fmaf(s0, b.y, a0.y);
            a0.z = fmaf(s0, b.z, a0.z); a0.w = fmaf(s0, b.w, a0.w);
            a1.x = fmaf(s1, b.x, a1.x); a1.y = fmaf(s1, b.y, a1.y);
            a1.z = fmaf(s1, b.z, a1.z); a1.w = fmaf(s1, b.w, a1.w);
        }
        pacc[0][kc][j4] = a0;
        pacc[1][kc][j4] = a1;
    }
    __syncthreads();

    const int r = t / 384;                 // row-half: waves 0-5 -> 0, 6-11 -> 1
    const int u = t - r * 384;             // 0..383

    {   // reduce 8 k-chunks; flat float view per row: [kc*384 + u]
        const float* pf = (const float*)pacc[r];
        float dot = 0.0f;
        #pragma unroll
        for (int c = 0; c < 8; ++c) dot += pf[c * 384 + u];
        srow[r][u] = fmaf(dot, HSCALE, HSCALE);
    }
    __syncthreads();

    // ---- counting sort per row ----
    const float vraw = srow[r][u];
    int b = (int)(vraw * BSCALE);
    b = b < 0 ? 0 : (b > NBUCK - 1 ? NBUCK - 1 : b);
    const int slot = atomicAdd(&hist[r][b], 1);
    __syncthreads();

    if (wave == 0 || wave == 6) {          // one scan wave per row
        const int rr = wave / 6;
        const int s0 = hist[rr][lane * 4 + 0], s1 = hist[rr][lane * 4 + 1];
        const int s2 = hist[rr][lane * 4 + 2], s3 = hist[rr][lane * 4 + 3];
        const int sum = s0 + s1 + s2 + s3;
        int inc = sum;
        #pragma unroll
        for (int off = 1; off < 64; off <<= 1) {
            int uu = __shfl_up(inc, off, 64);
            if (lane >= off) inc += uu;
        }
        const int base = inc - sum;
        pre[rr][lane * 4 + 0] = base;
        pre[rr][lane * 4 + 1] = base + s0;
        pre[rr][lane * 4 + 2] = base + s0 + s1;
        pre[rr][lane * 4 + 3] = base + s0 + s1 + s2;
        if (lane == 63) pre[rr][NBUCK] = inc;    // = 384
    }
    __syncthreads();

    {
        const int pos = pre[r][b] + slot;
        vsort[r][pos] = vraw;
        sidx[r][pos]  = u;
    }
    __syncthreads();

    // ---- soft window at sorted position u of row r ----
    const int   nrow  = n0 + r;
    const float ri    = vsort[r][u];
    const int   iorig = sidx[r][u];
    const float sn    = srow[r][nrow];

    int Blo = (int)((ri - WWIN) * BSCALE);
    int Bhi = (int)((ri + WWIN) * BSCALE);
    Blo = Blo < 0 ? 0 : (Blo > NBUCK - 1 ? NBUCK - 1 : Blo);
    Bhi = Bhi < 0 ? 0 : (Bhi > NBUCK - 1 ? NBUCK - 1 : Bhi);
    const int lo = pre[r][Blo];        // below: term ~ 0
    const int hi = pre[r][Bhi + 1];    // at/above: term ~ 1

    // pair-rcp: 1/(1+a) + 1/(1+b) = (2+(a+b)) * rcp(1+(a+b)+a*b)
    // window bounds |ri-v| <= ~18 => a,b <= 2.6e5, ab <= 7e10: fp32-safe.
    float acc = 0.0f;
    int q = lo;
    for (; q + 2 <= hi; q += 2) {
        float a = __builtin_amdgcn_exp2f(ri - vsort[r][q]);
        float bb = __builtin_amdgcn_exp2f(ri - vsort[r][q + 1]);
        float e = a + bb;
        float f = a * bb;
        acc = fmaf(2.0f + e, __builtin_amdgcn_rcpf(1.0f + e + f), acc);
    }
    if (q < hi)
        acc += __builtin_amdgcn_rcpf(1.0f + __builtin_amdgcn_exp2f(ri - vsort[r][q]));
    float sum_all = (float)(NN - hi) + acc;

    // diagonal (c == nrow) correction, bucket-consistent with the window
    int bn = (int)(sn * BSCALE);
    bn = bn < 0 ? 0 : (bn > NBUCK - 1 ? NBUCK - 1 : bn);
    float cd = 0.0f;
    if (bn > Bhi)       cd = 1.0f;
    else if (bn >= Blo) cd = __builtin_amdgcn_rcpf(1.0f + __builtin_amdgcn_exp2f(ri - sn));
    // self term (sigma(0)=0.5) always in-window: ind = 1 + sum - 0.5 - cd
    const float ind = 0.5f + sum_all - cd;

    // ---- dcg term ----
    float dcg_i = 0.0f;
    if (iorig != nrow) {               // permutation covers all 383 real cols
        const int gd = gt[iorig] - gt[nrow];
        const int gg = gd < 0 ? -gd : gd;
        dcg_i = (float)((1 << (10 - gg)) - 1) / __builtin_amdgcn_logf(ind + 1.0f);
    }

    #pragma unroll
    for (int off = 32; off > 0; off >>= 1) dcg_i += __shfl_down(dcg_i, off, 64);
    if (lane == 0) redd[wave] = dcg_i;
    __syncthreads();
    if (t == 0)
        ndcg[n0] = (redd[0] + redd[1] + redd[2] + redd[3] + redd[4] + redd[5])
                   / idcg_tab[gt[n0]];
    if (t == 384)
        ndcg[n0 + 1] = (redd[6] + redd[7] + redd[8] + redd[9] + redd[10] + redd[11])
                       / idcg_tab[gt[n0 + 1]];
}

__global__ __launch_bounds__(384) void dgc_final(const float* __restrict__ ndcg,
                                                 float* __restrict__ out) {
    __shared__ float red[6];
    const int t    = threadIdx.x;
    const int lane = t & 63;
    const int wave = t >> 6;
    float nd = ndcg[t];
    #pragma unroll
    for (int off = 32; off > 0; off >>= 1) nd += __shfl_down(nd, off, 64);
    if (lane == 0) red[wave] = nd;
    __syncthreads();
    if (t == 0) {
        float s = 0.0f;
        for (int w = 0; w < 6; ++w) s += red[w];
        out[0] = 1.0f - s / (float)NN;
    }
}

extern "C" void kernel_launch(void* const* d_in, const int* in_sizes, int n_in,
                              void* d_out, int out_size, void* d_ws, size_t ws_size,
                              hipStream_t stream) {
    const float* ranking = (const float*)d_in[0];
    const int*   gt      = (const int*)d_in[1];
    float*       out     = (float*)d_out;

    float* XT   = (float*)d_ws;                  // 256*384
    float* XN   = XT + (size_t)DD * NN;          // 384*256
    float* ndcg = XN + (size_t)NN * DD;          // 384
    float* tab  = ndcg + NN;                     // 6 (+pad)

    dgc_normT<<<25, 256, 0, stream>>>(ranking, gt, XT, XN, tab);
    dgc_fused<<<NN / 2, 768, 0, stream>>>(XT, XN, gt, tab, ndcg);
    dgc_final<<<1, 384, 0, stream>>>(ndcg, out);
}